// Round 15
// baseline (335.300 us; speedup 1.0000x reference)
//
#include <hip/hip_runtime.h>
#include <hip/hip_bf16.h>
#include <stdint.h>

#define KTOT 8192
#define BM 32
#define BK 128
#define KSPLIT 4
#define KCHUNK (KTOT / KSPLIT)   // 2048
#define NIT (KCHUNK / BK)        // 16

typedef __attribute__((ext_vector_type(8))) __bf16 bf16x8;
typedef __attribute__((ext_vector_type(4))) float f32x4;

__device__ __forceinline__ unsigned short f2bf(float f) {
  union { float f; unsigned int u; } a;
  a.f = f;
  unsigned int r = (a.u + 0x7fffu + ((a.u >> 16) & 1u)) >> 16;
  return (unsigned short)r;
}

__device__ __forceinline__ uint2 pack4(f32x4 v) {
  union { unsigned short h[4]; uint2 u; } pk;
  pk.h[0] = f2bf(v[0]); pk.h[1] = f2bf(v[1]);
  pk.h[2] = f2bf(v[2]); pk.h[3] = f2bf(v[3]);
  return pk.u;
}

// Barrier that drains LDS only — global prefetches stay in flight (T4).
__device__ __forceinline__ void block_bar() {
  asm volatile("s_waitcnt lgkmcnt(0)" ::: "memory");
  __builtin_amdgcn_s_barrier();
  __builtin_amdgcn_sched_barrier(0);
}

// x [8192][64] f32  ->  xt [64][8192] bf16 (transposed)
__global__ __launch_bounds__(256) void xpose_f32_bf16(const float* __restrict__ x,
                                                      __hip_bfloat16* __restrict__ xt) {
  __shared__ unsigned short tile[64][72];
  const int r0 = blockIdx.x * 64;
  const int t = threadIdx.x;
  const int a = t >> 4;
  const int c4 = (t & 15) * 4;
#pragma unroll
  for (int rep = 0; rep < 4; ++rep) {
    int r = a + rep * 16;
    f32x4 v = __builtin_nontemporal_load(
        reinterpret_cast<const f32x4*>(x + (size_t)(r0 + r) * 64 + c4));
    tile[c4 + 0][r] = f2bf(v[0]);
    tile[c4 + 1][r] = f2bf(v[1]);
    tile[c4 + 2][r] = f2bf(v[2]);
    tile[c4 + 3][r] = f2bf(v[3]);
  }
  __syncthreads();
#pragma unroll
  for (int rep = 0; rep < 4; ++rep) {
    int j = a + rep * 16;
    uint2 v = *reinterpret_cast<const uint2*>(&tile[j][c4]);
    *reinterpret_cast<uint2*>((unsigned short*)xt + (size_t)j * KTOT + r0 + c4) = v;
  }
}

// part[kc][col][row] (f32, [KSPLIT][128][8192]) = raw C partials of
// C = A(f32 [8192][8192]) @ B, B transposed bf16 BT[128][8192].
// BM=32, 256 threads (4 waves), grid 1024 -> 4 independent barrier domains
// per CU. Wave w owns cols {w*16, 64+w*16} x 2 M-tiles. A reg->bf16->LDS
// (XOR swizzle) dbuf with DEPTH-2 register prefetch; B direct global->reg
// per phase (L2-hot); lgkm-only barriers; K-phase rotation; XCD-affine kc.
__global__ __launch_bounds__(256, 4) void gemm_part(
    const float* __restrict__ A, const __hip_bfloat16* __restrict__ BTv,
    float* __restrict__ part) {
  constexpr int SZ_A = BM * BK * 2;   // 8 KiB
  __shared__ __align__(16) unsigned char smem[2 * SZ_A];   // 16 KiB
  const unsigned short* BT = (const unsigned short*)BTv;

  const int bid = blockIdx.x;
  const int kc = (bid & 7) >> 1;                   // XCD-affine K-chunk
  const int mblk = ((bid >> 3) << 1) | (bid & 1);  // 0..255
  const int r0 = mblk * BM;
  const int kbase = kc * KCHUNK;
  const int it0 = mblk & (NIT - 1);                // K-phase rotation

  const int t = threadIdx.x;
  const int l = t & 63;
  const int w = t >> 6;                            // 0..3

  // ---- A staging: 32x128 f32 tile, 4 f32x4 per thread ----
  const float* aptr[4];
  int loff[4];
#pragma unroll
  for (int r = 0; r < 4; ++r) {
    int idx = t + r * 256;
    int m = idx >> 5, c4 = idx & 31;               // row 0..31, f32x4-col 0..31
    aptr[r] = A + (size_t)(r0 + m) * KTOT + kbase + c4 * 4;
    loff[r] = m * 256 + ((c4 * 8) ^ ((m & 7) << 4));
  }

  // ---- compute roles: 2 col-tiles per wave ----
  const int lr = l & 15;
  const int g = l >> 4;
  const int col = w * 16 + lr;                     // col-tile 0; tile 1 = +64
  const unsigned short* bptr0 = BT + (size_t)col * KTOT + kbase + g * 8;
  const unsigned short* bptr1 = bptr0 + (size_t)64 * KTOT;
  const int asw = (lr & 7) << 4;

  f32x4 acc[2][2];
  const f32x4 fzero = {0.f, 0.f, 0.f, 0.f};
#pragma unroll
  for (int ct = 0; ct < 2; ++ct)
#pragma unroll
    for (int mt = 0; mt < 2; ++mt) acc[ct][mt] = fzero;

  f32x4 av0[4], av1[4];
  bf16x8 Bf[4];
  unsigned char* lds0 = smem;
  unsigned char* lds1 = smem + SZ_A;

  auto kof = [&](int s) { return ((s + it0) & (NIT - 1)) * BK; };

#define LOAD_A(AV, K0)                                                        \
  _Pragma("unroll") for (int r = 0; r < 4; ++r)                               \
      AV[r] = __builtin_nontemporal_load(                                     \
          reinterpret_cast<const f32x4*>(aptr[r] + (K0)));
#define WRITE_A(LDS, AV)                                                      \
  _Pragma("unroll") for (int r = 0; r < 4; ++r)                               \
      *reinterpret_cast<uint2*>((LDS) + loff[r]) = pack4(AV[r]);
#define COMPUTE(LDS, K0)                                                      \
  _Pragma("unroll") for (int ct = 0; ct < 2; ++ct) {                          \
    const unsigned short* bp_ = ct ? bptr1 : bptr0;                           \
    _Pragma("unroll") for (int ks = 0; ks < 4; ++ks)                          \
        Bf[ks] = *reinterpret_cast<const bf16x8*>(bp_ + (K0) + ks * 32);      \
    _Pragma("unroll") for (int ks = 0; ks < 4; ++ks) {                        \
      _Pragma("unroll") for (int mt = 0; mt < 2; ++mt) {                      \
        bf16x8 af_ = *reinterpret_cast<const bf16x8*>(                        \
            (LDS) + (mt * 16 + lr) * 256 + ((ks * 64 + g * 16) ^ asw));       \
        acc[ct][mt] = __builtin_amdgcn_mfma_f32_16x16x32_bf16(                \
            af_, Bf[ks], acc[ct][mt], 0, 0, 0);                               \
      }                                                                       \
    }                                                                         \
  }

  // prologue: rotated tiles 0,1 in flight; tile 0 -> lds0
  LOAD_A(av0, kof(0));
  LOAD_A(av1, kof(1));
  WRITE_A(lds0, av0);
  block_bar();

#pragma unroll 1
  for (int s = 0; s < NIT; s += 2) {
    // tile s (set 0, lds0)
    if (s + 1 < NIT) { WRITE_A(lds1, av1); }        // av1 = tile s+1
    if (s + 2 < NIT) { LOAD_A(av0, kof(s + 2)); }   // depth-2 prefetch
    COMPUTE(lds0, kof(s));
    if (s + 1 < NIT) block_bar();
    // tile s+1 (set 1, lds1)
    if (s + 1 < NIT) {
      if (s + 2 < NIT) { WRITE_A(lds0, av0); }      // av0 = tile s+2
      if (s + 3 < NIT) { LOAD_A(av1, kof(s + 3)); }
      COMPUTE(lds1, kof(s + 1));
      if (s + 2 < NIT) block_bar();
    }
  }

  // raw partial store (non-temporal)
#pragma unroll
  for (int ct = 0; ct < 2; ++ct) {
    float* pp = part + (size_t)(kc * 128 + col + ct * 64) * KTOT + r0 + g * 4;
#pragma unroll
    for (int mt = 0; mt < 2; ++mt)
      __builtin_nontemporal_store(acc[ct][mt],
                                  reinterpret_cast<f32x4*>(pp + mt * 16));
  }
#undef LOAD_A
#undef WRITE_A
#undef COMPUTE
}

// Combine KSPLIT partials + epilogue, separate halves (lo: cols 0-63, hi: 64-127).
__global__ __launch_bounds__(256) void reduce_sep(
    const float* __restrict__ part, float* __restrict__ out,
    const float* s_lo_p, const float* s_hi_p,
    const float* __restrict__ add_ptr, const float* add_s_p,
    __hip_bfloat16* bt_lo, __hip_bfloat16* bt_hi,
    int base_lo, int base_hi, int accum) {
  const int t = threadIdx.x;
  const int col = t & 127;
  const int rbase = blockIdx.x * 32 + (t >> 7) * 16;
  const float* p0 = part + (size_t)col * KTOT + rbase;
  const bool hi = col >= 64;
  const int col64 = hi ? col - 64 : col;
  __hip_bfloat16* bt = hi ? bt_hi : bt_lo;
  const int obase = hi ? base_hi : base_lo;
  const float s = hi ? (s_hi_p ? *s_hi_p : 0.f) : (s_lo_p ? *s_lo_p : 0.f);
  const float was = add_s_p ? *add_s_p : 0.f;
#pragma unroll
  for (int i = 0; i < 4; ++i) {
    f32x4 c = __builtin_nontemporal_load(
        reinterpret_cast<const f32x4*>(p0 + 4 * i));
#pragma unroll
    for (int k = 1; k < KSPLIT; ++k)
      c += __builtin_nontemporal_load(reinterpret_cast<const f32x4*>(
          p0 + (size_t)k * 128 * KTOT + 4 * i));
    if (bt)
      *reinterpret_cast<uint2*>((unsigned short*)bt + (size_t)col64 * KTOT + rbase + 4 * i) =
          pack4(c);
    if (obase >= 0) {
#pragma unroll
      for (int j = 0; j < 4; ++j) {
        int row = rbase + 4 * i + j;
        float v = s * c[j];
        if (add_ptr && !hi) v = fmaf(was, add_ptr[(size_t)row * 64 + col64], v);
        if (accum) v += out[(size_t)row * 128 + obase + col64];
        out[(size_t)row * 128 + obase + col64] = v;
      }
    }
  }
}

// Combine partials + cross-half epilogue: out[:,64+c] = sl*lo[c] + sh*hi[c];
// bt_lo = raw lo (bf16 transposed).
__global__ __launch_bounds__(256) void reduce_comb(
    const float* __restrict__ part, float* __restrict__ out,
    const float* s_lo_p, const float* s_hi_p, __hip_bfloat16* bt_lo) {
  const int t = threadIdx.x;
  const int c = t & 63;
  const int rbase = blockIdx.x * 32 + (t >> 6) * 8;
  const float* pl = part + (size_t)c * KTOT + rbase;
  const float* ph = part + (size_t)(c + 64) * KTOT + rbase;
  const float sl = *s_lo_p, sh = *s_hi_p;
#pragma unroll
  for (int i = 0; i < 2; ++i) {
    f32x4 lo = __builtin_nontemporal_load(reinterpret_cast<const f32x4*>(pl + 4 * i));
    f32x4 hv = __builtin_nontemporal_load(reinterpret_cast<const f32x4*>(ph + 4 * i));
#pragma unroll
    for (int k = 1; k < KSPLIT; ++k) {
      lo += __builtin_nontemporal_load(reinterpret_cast<const f32x4*>(
          pl + (size_t)k * 128 * KTOT + 4 * i));
      hv += __builtin_nontemporal_load(reinterpret_cast<const f32x4*>(
          ph + (size_t)k * 128 * KTOT + 4 * i));
    }
    *reinterpret_cast<uint2*>((unsigned short*)bt_lo + (size_t)c * KTOT + rbase + 4 * i) =
        pack4(lo);
#pragma unroll
    for (int j = 0; j < 4; ++j) {
      int row = rbase + 4 * i + j;
      out[(size_t)row * 128 + 64 + c] = sl * lo[j] + sh * hv[j];
    }
  }
}

extern "C" void kernel_launch(void* const* d_in, const int* in_sizes, int n_in,
                              void* d_out, int out_size, void* d_ws, size_t ws_size,
                              hipStream_t stream) {
  const float* A_p = (const float*)d_in[0];
  const float* A_n = (const float*)d_in[1];
  const float* x_p = (const float*)d_in[2];
  const float* x_n = (const float*)d_in[3];
  const float* w_p = (const float*)d_in[4];  // [3]
  const float* w_n = (const float*)d_in[5];  // [3]
  float* out = (float*)d_out;                // [8192][128]

  // ws layout (21 MiB):
  //   BTbig [192][8192] bf16: rows 0-63 x_p^T, 64-127 x_n^T, 128-191 Y1^T
  //   B3T   [128][8192] bf16: rows 0-63 P1^T, 64-127 T1^T
  //   part  [KSPLIT][128][8192] f32
  __hip_bfloat16* BTbig = (__hip_bfloat16*)d_ws;
  __hip_bfloat16* B3T = BTbig + (size_t)192 * KTOT;
  float* part = (float*)(B3T + (size_t)128 * KTOT);

  xpose_f32_bf16<<<128, 256, 0, stream>>>(x_p, BTbig);
  xpose_f32_bf16<<<128, 256, 0, stream>>>(x_n, BTbig + (size_t)64 * KTOT);

  // G1: [P1|Y1] = A_p @ [x_p|x_n]
  gemm_part<<<1024, 256, 0, stream>>>(A_p, BTbig, part);
  // out[:,0:64] = wp0*x_p + wp1*P1; emit P1^T -> B3T[0:64], Y1^T -> BTbig[128:192]
  reduce_sep<<<256, 256, 0, stream>>>(part, out, w_p + 1, nullptr, x_p, w_p + 0,
                                      B3T, BTbig + (size_t)128 * KTOT, 0, -1, 0);

  // G2': [T1|T3] = A_n @ [x_n|Y1]
  gemm_part<<<1024, 256, 0, stream>>>(A_n, BTbig + (size_t)64 * KTOT, part);
  // out[:,64:128] = wn0*T1 + wn2*T3; emit T1^T -> B3T[64:128]
  reduce_comb<<<256, 256, 0, stream>>>(part, out, w_n + 0, w_n + 2,
                                       B3T + (size_t)64 * KTOT);

  // G3: [P2|T2] = A_p @ [P1|T1]
  gemm_part<<<1024, 256, 0, stream>>>(A_p, B3T, part);
  // out[:,0:64] += wp2*P2; out[:,64:128] += wn1*T2
  reduce_sep<<<256, 256, 0, stream>>>(part, out, w_p + 2, w_n + 1, nullptr, nullptr,
                                      nullptr, nullptr, 0, 64, 1);
}

// Round 16
// 278.395 us; speedup vs baseline: 1.2044x; 1.2044x over previous
//
#include <hip/hip_runtime.h>
#include <hip/hip_bf16.h>
#include <stdint.h>

#define KTOT 8192
#define BM 64
#define BK 128
#define KSPLIT 4
#define KCHUNK (KTOT / KSPLIT)   // 2048
#define SK 256                   // staging window: 2 BK tiles, 1KB/row f32
#define NST (KCHUNK / SK)        // 8 staging steps
#define SZ_TILE (BM * BK * 2)    // 16 KiB per BK tile
#define SZ_BUF (2 * SZ_TILE)     // 32 KiB per staging buffer

typedef __attribute__((ext_vector_type(8))) __bf16 bf16x8;
typedef __attribute__((ext_vector_type(4))) float f32x4;

__device__ __forceinline__ unsigned short f2bf(float f) {
  union { float f; unsigned int u; } a;
  a.f = f;
  unsigned int r = (a.u + 0x7fffu + ((a.u >> 16) & 1u)) >> 16;
  return (unsigned short)r;
}

__device__ __forceinline__ uint2 pack4(f32x4 v) {
  union { unsigned short h[4]; uint2 u; } pk;
  pk.h[0] = f2bf(v[0]); pk.h[1] = f2bf(v[1]);
  pk.h[2] = f2bf(v[2]); pk.h[3] = f2bf(v[3]);
  return pk.u;
}

// Barrier that drains LDS only — global prefetches stay in flight (T4).
__device__ __forceinline__ void block_bar() {
  asm volatile("s_waitcnt lgkmcnt(0)" ::: "memory");
  __builtin_amdgcn_s_barrier();
  __builtin_amdgcn_sched_barrier(0);
}

// x [8192][64] f32  ->  xt [64][8192] bf16 (transposed)
__global__ __launch_bounds__(256) void xpose_f32_bf16(const float* __restrict__ x,
                                                      __hip_bfloat16* __restrict__ xt) {
  __shared__ unsigned short tile[64][72];
  const int r0 = blockIdx.x * 64;
  const int t = threadIdx.x;
  const int a = t >> 4;
  const int c4 = (t & 15) * 4;
#pragma unroll
  for (int rep = 0; rep < 4; ++rep) {
    int r = a + rep * 16;
    f32x4 v = __builtin_nontemporal_load(
        reinterpret_cast<const f32x4*>(x + (size_t)(r0 + r) * 64 + c4));
    tile[c4 + 0][r] = f2bf(v[0]);
    tile[c4 + 1][r] = f2bf(v[1]);
    tile[c4 + 2][r] = f2bf(v[2]);
    tile[c4 + 3][r] = f2bf(v[3]);
  }
  __syncthreads();
#pragma unroll
  for (int rep = 0; rep < 4; ++rep) {
    int j = a + rep * 16;
    uint2 v = *reinterpret_cast<const uint2*>(&tile[j][c4]);
    *reinterpret_cast<uint2*>((unsigned short*)xt + (size_t)j * KTOT + r0 + c4) = v;
  }
}

// part[kc][col][row] (f32, [KSPLIT][128][8192]) = raw C partials of
// C = A(f32 [8192][8192]) @ B, B transposed bf16 BT[128][8192].
// A staged in SK=256 windows: each wave instruction reads ONE ROW'S 1 KB
// CONTIGUOUS SPAN (64 lanes x 16 B) — the 5.4 TB/s pattern (R13 probe).
// vmcnt-order-correct pipeline: B loads for step s are issued BEFORE the
// A prefetch for step s+1, so MFMA B-waits never drain the A stream.
// lgkm-only barrier per step; K-rotation; XCD-affine kc; B direct from L2.
__global__ __launch_bounds__(512, 4) void gemm_part(
    const float* __restrict__ A, const __hip_bfloat16* __restrict__ BTv,
    float* __restrict__ part) {
  __shared__ __align__(16) unsigned char smem[2 * SZ_BUF];   // 64 KiB
  const unsigned short* BT = (const unsigned short*)BTv;

  const int bid = blockIdx.x;
  const int kc = (bid & 7) >> 1;                 // XCD-affine K-chunk
  const int mblk = ((bid >> 3) << 1) | (bid & 1);
  const int r0 = mblk * BM;
  const int kbase = kc * KCHUNK;
  const int it0 = mblk & (NST - 1);              // staging-step rotation

  const int t = threadIdx.x;
  const int l = t & 63;
  const int w = t >> 6;

  // ---- A staging: wave w stages rows w*8..w*8+7; instruction r reads row
  // w*8+r's [koff + l*4 .. +3] — 1 KB contiguous per wave instruction.
  const float* abase = A + (size_t)(r0 + w * 8) * KTOT + kbase + l * 4;
  // LDS dest: tile (l>>5), row w*8+r, byte ((l&31)*8) ^ (r<<4)  [row&7 == r]
  int loff[8];
#pragma unroll
  for (int r = 0; r < 8; ++r)
    loff[r] = (l >> 5) * SZ_TILE + (w * 8 + r) * 256 + (((l & 31) * 8) ^ (r << 4));

  // ---- compute roles ----
  const int lr = l & 15;
  const int g = l >> 4;
  const int col = w * 16 + lr;
  const unsigned short* bptr = BT + (size_t)col * KTOT + kbase + g * 8;
  const int asw = (lr & 7) << 4;

  f32x4 acc[4];
  const f32x4 fzero = {0.f, 0.f, 0.f, 0.f};
#pragma unroll
  for (int mt = 0; mt < 4; ++mt) acc[mt] = fzero;

  f32x4 av[8];
  bf16x8 Bf[8];

  auto koff = [&](int s) { return ((s + it0) & (NST - 1)) * SK; };

#define LOAD_A(K0)                                                            \
  _Pragma("unroll") for (int r = 0; r < 8; ++r)                               \
      av[r] = __builtin_nontemporal_load(reinterpret_cast<const f32x4*>(      \
          abase + (size_t)r * KTOT + (K0)));
#define WRITE_A(BUF)                                                          \
  _Pragma("unroll") for (int r = 0; r < 8; ++r)                               \
      *reinterpret_cast<uint2*>((BUF) + loff[r]) = pack4(av[r]);
#define LOAD_B8(K0)                                                           \
  _Pragma("unroll") for (int ks = 0; ks < 8; ++ks)                            \
      Bf[ks] = *reinterpret_cast<const bf16x8*>(bptr + (K0) + ks * 32);
#define COMPUTE(TILE, BO)                                                     \
  _Pragma("unroll") for (int ks = 0; ks < 4; ++ks) {                          \
    _Pragma("unroll") for (int mt = 0; mt < 4; ++mt) {                        \
      bf16x8 af_ = *reinterpret_cast<const bf16x8*>(                          \
          (TILE) + (mt * 16 + lr) * 256 + ((ks * 64 + g * 16) ^ asw));        \
      acc[mt] = __builtin_amdgcn_mfma_f32_16x16x32_bf16(af_, Bf[(BO) + ks],   \
                                                        acc[mt], 0, 0, 0);    \
    }                                                                         \
  }

  // prologue: step 0's A in flight
  LOAD_A(koff(0));

#pragma unroll 1
  for (int s = 0; s < NST; ++s) {
    unsigned char* buf = smem + (s & 1) * SZ_BUF;
    WRITE_A(buf);                    // waits (counted) for this step's av only
    block_bar();                     // lgkm drain; vmem prefetch unaffected
    LOAD_B8(koff(s));                // B FIRST (oldest outstanding -> cheap wait)
    if (s + 1 < NST) { LOAD_A(koff(s + 1)); }   // A prefetch AFTER B
    COMPUTE(buf, 0);                 // tile even: waits B[0..3], av stays in flight
    COMPUTE(buf + SZ_TILE, 4);       // tile odd:  waits B[4..7]
  }

  // raw partial store (non-temporal)
  float* pp = part + (size_t)(kc * 128 + col) * KTOT + r0 + g * 4;
#pragma unroll
  for (int mt = 0; mt < 4; ++mt)
    __builtin_nontemporal_store(acc[mt], reinterpret_cast<f32x4*>(pp + mt * 16));
#undef LOAD_A
#undef WRITE_A
#undef LOAD_B8
#undef COMPUTE
}

// Combine KSPLIT partials + epilogue, separate halves (lo: cols 0-63, hi: 64-127).
__global__ __launch_bounds__(256) void reduce_sep(
    const float* __restrict__ part, float* __restrict__ out,
    const float* s_lo_p, const float* s_hi_p,
    const float* __restrict__ add_ptr, const float* add_s_p,
    __hip_bfloat16* bt_lo, __hip_bfloat16* bt_hi,
    int base_lo, int base_hi, int accum) {
  const int t = threadIdx.x;
  const int col = t & 127;
  const int rbase = blockIdx.x * 32 + (t >> 7) * 16;
  const float* p0 = part + (size_t)col * KTOT + rbase;
  const bool hi = col >= 64;
  const int col64 = hi ? col - 64 : col;
  __hip_bfloat16* bt = hi ? bt_hi : bt_lo;
  const int obase = hi ? base_hi : base_lo;
  const float s = hi ? (s_hi_p ? *s_hi_p : 0.f) : (s_lo_p ? *s_lo_p : 0.f);
  const float was = add_s_p ? *add_s_p : 0.f;
#pragma unroll
  for (int i = 0; i < 4; ++i) {
    f32x4 c = __builtin_nontemporal_load(
        reinterpret_cast<const f32x4*>(p0 + 4 * i));
#pragma unroll
    for (int k = 1; k < KSPLIT; ++k)
      c += __builtin_nontemporal_load(reinterpret_cast<const f32x4*>(
          p0 + (size_t)k * 128 * KTOT + 4 * i));
    if (bt)
      *reinterpret_cast<uint2*>((unsigned short*)bt + (size_t)col64 * KTOT + rbase + 4 * i) =
          pack4(c);
    if (obase >= 0) {
#pragma unroll
      for (int j = 0; j < 4; ++j) {
        int row = rbase + 4 * i + j;
        float v = s * c[j];
        if (add_ptr && !hi) v = fmaf(was, add_ptr[(size_t)row * 64 + col64], v);
        if (accum) v += out[(size_t)row * 128 + obase + col64];
        out[(size_t)row * 128 + obase + col64] = v;
      }
    }
  }
}

// Combine partials + cross-half epilogue: out[:,64+c] = sl*lo[c] + sh*hi[c];
// bt_lo = raw lo (bf16 transposed).
__global__ __launch_bounds__(256) void reduce_comb(
    const float* __restrict__ part, float* __restrict__ out,
    const float* s_lo_p, const float* s_hi_p, __hip_bfloat16* bt_lo) {
  const int t = threadIdx.x;
  const int c = t & 63;
  const int rbase = blockIdx.x * 32 + (t >> 6) * 8;
  const float* pl = part + (size_t)c * KTOT + rbase;
  const float* ph = part + (size_t)(c + 64) * KTOT + rbase;
  const float sl = *s_lo_p, sh = *s_hi_p;
#pragma unroll
  for (int i = 0; i < 2; ++i) {
    f32x4 lo = __builtin_nontemporal_load(reinterpret_cast<const f32x4*>(pl + 4 * i));
    f32x4 hv = __builtin_nontemporal_load(reinterpret_cast<const f32x4*>(ph + 4 * i));
#pragma unroll
    for (int k = 1; k < KSPLIT; ++k) {
      lo += __builtin_nontemporal_load(reinterpret_cast<const f32x4*>(
          pl + (size_t)k * 128 * KTOT + 4 * i));
      hv += __builtin_nontemporal_load(reinterpret_cast<const f32x4*>(
          ph + (size_t)k * 128 * KTOT + 4 * i));
    }
    *reinterpret_cast<uint2*>((unsigned short*)bt_lo + (size_t)c * KTOT + rbase + 4 * i) =
        pack4(lo);
#pragma unroll
    for (int j = 0; j < 4; ++j) {
      int row = rbase + 4 * i + j;
      out[(size_t)row * 128 + 64 + c] = sl * lo[j] + sh * hv[j];
    }
  }
}

extern "C" void kernel_launch(void* const* d_in, const int* in_sizes, int n_in,
                              void* d_out, int out_size, void* d_ws, size_t ws_size,
                              hipStream_t stream) {
  const float* A_p = (const float*)d_in[0];
  const float* A_n = (const float*)d_in[1];
  const float* x_p = (const float*)d_in[2];
  const float* x_n = (const float*)d_in[3];
  const float* w_p = (const float*)d_in[4];  // [3]
  const float* w_n = (const float*)d_in[5];  // [3]
  float* out = (float*)d_out;                // [8192][128]

  // ws layout (21 MiB):
  //   BTbig [192][8192] bf16: rows 0-63 x_p^T, 64-127 x_n^T, 128-191 Y1^T
  //   B3T   [128][8192] bf16: rows 0-63 P1^T, 64-127 T1^T
  //   part  [KSPLIT][128][8192] f32
  __hip_bfloat16* BTbig = (__hip_bfloat16*)d_ws;
  __hip_bfloat16* B3T = BTbig + (size_t)192 * KTOT;
  float* part = (float*)(B3T + (size_t)128 * KTOT);

  xpose_f32_bf16<<<128, 256, 0, stream>>>(x_p, BTbig);
  xpose_f32_bf16<<<128, 256, 0, stream>>>(x_n, BTbig + (size_t)64 * KTOT);

  // G1: [P1|Y1] = A_p @ [x_p|x_n]
  gemm_part<<<512, 512, 0, stream>>>(A_p, BTbig, part);
  // out[:,0:64] = wp0*x_p + wp1*P1; emit P1^T -> B3T[0:64], Y1^T -> BTbig[128:192]
  reduce_sep<<<256, 256, 0, stream>>>(part, out, w_p + 1, nullptr, x_p, w_p + 0,
                                      B3T, BTbig + (size_t)128 * KTOT, 0, -1, 0);

  // G2': [T1|T3] = A_n @ [x_n|Y1]
  gemm_part<<<512, 512, 0, stream>>>(A_n, BTbig + (size_t)64 * KTOT, part);
  // out[:,64:128] = wn0*T1 + wn2*T3; emit T1^T -> B3T[64:128]
  reduce_comb<<<256, 256, 0, stream>>>(part, out, w_n + 0, w_n + 2,
                                       B3T + (size_t)64 * KTOT);

  // G3: [P2|T2] = A_p @ [P1|T1]
  gemm_part<<<512, 512, 0, stream>>>(A_p, B3T, part);
  // out[:,0:64] += wp2*P2; out[:,64:128] += wn1*T2
  reduce_sep<<<256, 256, 0, stream>>>(part, out, w_p + 2, w_n + 1, nullptr, nullptr,
                                      nullptr, nullptr, 0, 64, 1);
}

// Round 17
// 217.374 us; speedup vs baseline: 1.5425x; 1.2807x over previous
//
#include <hip/hip_runtime.h>
#include <hip/hip_bf16.h>
#include <stdint.h>

#define KTOT 8192
#define BM 64
#define BK 128
#define KSPLIT 4
#define KCHUNK (KTOT / KSPLIT)   // 2048
#define NIT (KCHUNK / BK)        // 16
#define TILE_BYTES (BM * BK * 2) // 16 KiB blocked-A tile image

typedef __attribute__((ext_vector_type(8))) __bf16 bf16x8;
typedef __attribute__((ext_vector_type(4))) float f32x4;

__device__ __forceinline__ unsigned short f2bf(float f) {
  union { float f; unsigned int u; } a;
  a.f = f;
  unsigned int r = (a.u + 0x7fffu + ((a.u >> 16) & 1u)) >> 16;
  return (unsigned short)r;
}

__device__ __forceinline__ uint2 pack4(f32x4 v) {
  union { unsigned short h[4]; uint2 u; } pk;
  pk.h[0] = f2bf(v[0]); pk.h[1] = f2bf(v[1]);
  pk.h[2] = f2bf(v[2]); pk.h[3] = f2bf(v[3]);
  return pk.u;
}

// Barrier that drains LDS only — global prefetches stay in flight (T4).
__device__ __forceinline__ void block_bar() {
  asm volatile("s_waitcnt lgkmcnt(0)" ::: "memory");
  __builtin_amdgcn_s_barrier();
  __builtin_amdgcn_sched_barrier(0);
}

// x [8192][64] f32  ->  xt [64][8192] bf16 (transposed)
__global__ __launch_bounds__(256) void xpose_f32_bf16(const float* __restrict__ x,
                                                      __hip_bfloat16* __restrict__ xt) {
  __shared__ unsigned short tile[64][72];
  const int r0 = blockIdx.x * 64;
  const int t = threadIdx.x;
  const int a = t >> 4;
  const int c4 = (t & 15) * 4;
#pragma unroll
  for (int rep = 0; rep < 4; ++rep) {
    int r = a + rep * 16;
    f32x4 v = __builtin_nontemporal_load(
        reinterpret_cast<const f32x4*>(x + (size_t)(r0 + r) * 64 + c4));
    tile[c4 + 0][r] = f2bf(v[0]);
    tile[c4 + 1][r] = f2bf(v[1]);
    tile[c4 + 2][r] = f2bf(v[2]);
    tile[c4 + 3][r] = f2bf(v[3]);
  }
  __syncthreads();
#pragma unroll
  for (int rep = 0; rep < 4; ++rep) {
    int j = a + rep * 16;
    uint2 v = *reinterpret_cast<const uint2*>(&tile[j][c4]);
    *reinterpret_cast<uint2*>((unsigned short*)xt + (size_t)j * KTOT + r0 + c4) = v;
  }
}

// R9 GEMM (proven 238 us base): part[kc][col][row] partials of C = A @ B,
// BT[128][8192] bf16. A reg->bf16->LDS (XOR swizzle) dbuf, depth-2 reg
// prefetch; B direct global->reg; lgkm-only barriers; K-phase rotation;
// XCD-affine kc. Partial stores REGULAR (L2/L3-retained, read by reduce).
// WBLK=1 additionally emits packed bf16 tile images to ablk.
template <int WBLK>
__global__ __launch_bounds__(512, 4) void gemm_part(
    const float* __restrict__ A, const __hip_bfloat16* __restrict__ BTv,
    float* __restrict__ part, unsigned char* __restrict__ ablk) {
  constexpr int SZ_A = BM * BK * 2;   // 16 KiB
  __shared__ __align__(16) unsigned char smem[2 * SZ_A];
  const unsigned short* BT = (const unsigned short*)BTv;

  const int bid = blockIdx.x;
  const int kc = (bid & 7) >> 1;                 // XCD-affine K-chunk
  const int mblk = ((bid >> 3) << 1) | (bid & 1);
  const int r0 = mblk * BM;
  const int kbase = kc * KCHUNK;
  const int it0 = mblk & (NIT - 1);              // K-phase rotation

  const int t = threadIdx.x;
  const int l = t & 63;
  const int w = t >> 6;

  const float* aptr[4];
  int loff[4];
#pragma unroll
  for (int r = 0; r < 4; ++r) {
    int idx = t + r * 512;
    int m = idx >> 5, c4 = idx & 31;
    aptr[r] = A + (size_t)(r0 + m) * KTOT + kbase + c4 * 4;
    loff[r] = m * 256 + ((c4 * 8) ^ ((m & 7) << 4));
  }
  unsigned char* tb0 =
      WBLK ? ablk + (size_t)(mblk * KSPLIT + kc) * NIT * TILE_BYTES : nullptr;

  const int lr = l & 15;
  const int g = l >> 4;
  const int col = w * 16 + lr;
  const unsigned short* bptr = BT + (size_t)col * KTOT + kbase + g * 8;
  const int asw = (lr & 7) << 4;

  f32x4 acc[4];
  const f32x4 fzero = {0.f, 0.f, 0.f, 0.f};
#pragma unroll
  for (int mt = 0; mt < 4; ++mt) acc[mt] = fzero;

  f32x4 av0[4], av1[4];
  bf16x8 Bf0[4], Bf1[4];
  unsigned char* lds0 = smem;
  unsigned char* lds1 = smem + SZ_A;

  auto kof = [&](int s) { return ((s + it0) & (NIT - 1)) * BK; };

#define LOAD_A(AV, K0)                                                        \
  _Pragma("unroll") for (int r = 0; r < 4; ++r)                               \
      AV[r] = __builtin_nontemporal_load(                                     \
          reinterpret_cast<const f32x4*>(aptr[r] + (K0)));
#define LOAD_B(BF, K0)                                                        \
  _Pragma("unroll") for (int ks = 0; ks < 4; ++ks)                            \
      BF[ks] = *reinterpret_cast<const bf16x8*>(bptr + (K0) + ks * 32);
#define WRITE_A(LDS, AV, RS)                                                  \
  _Pragma("unroll") for (int r = 0; r < 4; ++r) {                             \
    uint2 pk_ = pack4(AV[r]);                                                 \
    *reinterpret_cast<uint2*>((LDS) + loff[r]) = pk_;                         \
    if constexpr (WBLK)                                                       \
      *reinterpret_cast<uint2*>(tb0 + (size_t)(RS) * TILE_BYTES + loff[r]) =  \
          pk_;                                                                \
  }
#define COMPUTE(LDS, BF)                                                      \
  _Pragma("unroll") for (int ks = 0; ks < 4; ++ks) {                          \
    _Pragma("unroll") for (int mt = 0; mt < 4; ++mt) {                        \
      bf16x8 af_ = *reinterpret_cast<const bf16x8*>(                          \
          (LDS) + (mt * 16 + lr) * 256 + ((ks * 64 + g * 16) ^ asw));         \
      acc[mt] = __builtin_amdgcn_mfma_f32_16x16x32_bf16(af_, BF[ks], acc[mt], \
                                                        0, 0, 0);             \
    }                                                                         \
  }

  LOAD_A(av0, kof(0)); LOAD_B(Bf0, kof(0));
  LOAD_A(av1, kof(1)); LOAD_B(Bf1, kof(1));
  WRITE_A(lds0, av0, it0);
  block_bar();

#pragma unroll 1
  for (int s = 0; s < NIT; s += 2) {
    if (s + 1 < NIT) { WRITE_A(lds1, av1, (s + 1 + it0) & (NIT - 1)); }
    if (s + 2 < NIT) { LOAD_A(av0, kof(s + 2)); }
    COMPUTE(lds0, Bf0);
    if (s + 2 < NIT) { LOAD_B(Bf0, kof(s + 2)); }
    if (s + 1 < NIT) block_bar();
    if (s + 1 < NIT) {
      if (s + 2 < NIT) { WRITE_A(lds0, av0, (s + 2 + it0) & (NIT - 1)); }
      if (s + 3 < NIT) { LOAD_A(av1, kof(s + 3)); }
      COMPUTE(lds1, Bf1);
      if (s + 3 < NIT) { LOAD_B(Bf1, kof(s + 3)); }
      if (s + 2 < NIT) block_bar();
    }
  }

  // REGULAR partial store — keep in L2/L3 for the reduce pass.
  float* pp = part + (size_t)(kc * 128 + col) * KTOT + r0 + g * 4;
#pragma unroll
  for (int mt = 0; mt < 4; ++mt)
    *reinterpret_cast<f32x4*>(pp + mt * 16) = acc[mt];
#undef LOAD_A
#undef WRITE_A
}

// G3 variant: A from blocked bf16 tile images (dense 256 KB slab per block).
__global__ __launch_bounds__(512, 4) void gemm_blocked(
    const unsigned char* __restrict__ ablk, const __hip_bfloat16* __restrict__ BTv,
    float* __restrict__ part) {
  constexpr int SZ_A = BM * BK * 2;
  __shared__ __align__(16) unsigned char smem[2 * SZ_A];
  const unsigned short* BT = (const unsigned short*)BTv;

  const int bid = blockIdx.x;
  const int kc = (bid & 7) >> 1;
  const int mblk = ((bid >> 3) << 1) | (bid & 1);
  const int r0 = mblk * BM;
  const int kbase = kc * KCHUNK;
  const int it0 = mblk & (NIT - 1);

  const int t = threadIdx.x;
  const int l = t & 63;
  const int w = t >> 6;

  int loff[4];
#pragma unroll
  for (int r = 0; r < 4; ++r) {
    int idx = t + r * 512;
    int m = idx >> 5, c4 = idx & 31;
    loff[r] = m * 256 + ((c4 * 8) ^ ((m & 7) << 4));
  }
  const unsigned char* tb0 =
      ablk + (size_t)(mblk * KSPLIT + kc) * NIT * TILE_BYTES;

  const int lr = l & 15;
  const int g = l >> 4;
  const int col = w * 16 + lr;
  const unsigned short* bptr = BT + (size_t)col * KTOT + kbase + g * 8;
  const int asw = (lr & 7) << 4;

  f32x4 acc[4];
  const f32x4 fzero = {0.f, 0.f, 0.f, 0.f};
#pragma unroll
  for (int mt = 0; mt < 4; ++mt) acc[mt] = fzero;

  uint2 bv0[4], bv1[4];
  bf16x8 Bf0[4], Bf1[4];
  unsigned char* lds0 = smem;
  unsigned char* lds1 = smem + SZ_A;

  auto kof = [&](int s) { return ((s + it0) & (NIT - 1)) * BK; };
  auto rs = [&](int s) { return (s + it0) & (NIT - 1); };

#define LOAD_A(BV, RS)                                                        \
  _Pragma("unroll") for (int r = 0; r < 4; ++r)                               \
      BV[r] = *reinterpret_cast<const uint2*>(                                \
          tb0 + (size_t)(RS) * TILE_BYTES + loff[r]);
#define LOAD_B(BF, K0)                                                        \
  _Pragma("unroll") for (int ks = 0; ks < 4; ++ks)                            \
      BF[ks] = *reinterpret_cast<const bf16x8*>(bptr + (K0) + ks * 32);
#define WRITE_A(LDS, BV)                                                      \
  _Pragma("unroll") for (int r = 0; r < 4; ++r)                               \
      *reinterpret_cast<uint2*>((LDS) + loff[r]) = BV[r];
#define COMPUTE(LDS, BF)                                                      \
  _Pragma("unroll") for (int ks = 0; ks < 4; ++ks) {                          \
    _Pragma("unroll") for (int mt = 0; mt < 4; ++mt) {                        \
      bf16x8 af_ = *reinterpret_cast<const bf16x8*>(                          \
          (LDS) + (mt * 16 + lr) * 256 + ((ks * 64 + g * 16) ^ asw));         \
      acc[mt] = __builtin_amdgcn_mfma_f32_16x16x32_bf16(af_, BF[ks], acc[mt], \
                                                        0, 0, 0);             \
    }                                                                         \
  }

  LOAD_A(bv0, rs(0)); LOAD_B(Bf0, kof(0));
  LOAD_A(bv1, rs(1)); LOAD_B(Bf1, kof(1));
  WRITE_A(lds0, bv0);
  block_bar();

#pragma unroll 1
  for (int s = 0; s < NIT; s += 2) {
    if (s + 1 < NIT) { WRITE_A(lds1, bv1); }
    if (s + 2 < NIT) { LOAD_A(bv0, rs(s + 2)); }
    COMPUTE(lds0, Bf0);
    if (s + 2 < NIT) { LOAD_B(Bf0, kof(s + 2)); }
    if (s + 1 < NIT) block_bar();
    if (s + 1 < NIT) {
      if (s + 2 < NIT) { WRITE_A(lds0, bv0); }
      if (s + 3 < NIT) { LOAD_A(bv1, rs(s + 3)); }
      COMPUTE(lds1, Bf1);
      if (s + 3 < NIT) { LOAD_B(Bf1, kof(s + 3)); }
      if (s + 2 < NIT) block_bar();
    }
  }

  float* pp = part + (size_t)(kc * 128 + col) * KTOT + r0 + g * 4;
#pragma unroll
  for (int mt = 0; mt < 4; ++mt)
    *reinterpret_cast<f32x4*>(pp + mt * 16) = acc[mt];
#undef LOAD_A
#undef LOAD_B
#undef WRITE_A
#undef COMPUTE
}

// Combine KSPLIT partials + epilogue, separate halves (lo: cols 0-63, hi: 64-127).
// Partials read with REGULAR loads (L2/L3-resident).
__global__ __launch_bounds__(256) void reduce_sep(
    const float* __restrict__ part, float* __restrict__ out,
    const float* s_lo_p, const float* s_hi_p,
    const float* __restrict__ add_ptr, const float* add_s_p,
    __hip_bfloat16* bt_lo, __hip_bfloat16* bt_hi,
    int base_lo, int base_hi, int accum) {
  const int t = threadIdx.x;
  const int col = t & 127;
  const int rbase = blockIdx.x * 32 + (t >> 7) * 16;
  const float* p0 = part + (size_t)col * KTOT + rbase;
  const bool hi = col >= 64;
  const int col64 = hi ? col - 64 : col;
  __hip_bfloat16* bt = hi ? bt_hi : bt_lo;
  const int obase = hi ? base_hi : base_lo;
  const float s = hi ? (s_hi_p ? *s_hi_p : 0.f) : (s_lo_p ? *s_lo_p : 0.f);
  const float was = add_s_p ? *add_s_p : 0.f;
#pragma unroll
  for (int i = 0; i < 4; ++i) {
    f32x4 c = *reinterpret_cast<const f32x4*>(p0 + 4 * i);
#pragma unroll
    for (int k = 1; k < KSPLIT; ++k)
      c += *reinterpret_cast<const f32x4*>(p0 + (size_t)k * 128 * KTOT + 4 * i);
    if (bt)
      *reinterpret_cast<uint2*>((unsigned short*)bt + (size_t)col64 * KTOT + rbase + 4 * i) =
          pack4(c);
    if (obase >= 0) {
#pragma unroll
      for (int j = 0; j < 4; ++j) {
        int row = rbase + 4 * i + j;
        float v = s * c[j];
        if (add_ptr && !hi) v = fmaf(was, add_ptr[(size_t)row * 64 + col64], v);
        if (accum) v += out[(size_t)row * 128 + obase + col64];
        out[(size_t)row * 128 + obase + col64] = v;
      }
    }
  }
}

// Combine partials + cross-half epilogue: out[:,64+c] = sl*lo[c] + sh*hi[c];
// bt_lo = raw lo (bf16 transposed).
__global__ __launch_bounds__(256) void reduce_comb(
    const float* __restrict__ part, float* __restrict__ out,
    const float* s_lo_p, const float* s_hi_p, __hip_bfloat16* bt_lo) {
  const int t = threadIdx.x;
  const int c = t & 63;
  const int rbase = blockIdx.x * 32 + (t >> 6) * 8;
  const float* pl = part + (size_t)c * KTOT + rbase;
  const float* ph = part + (size_t)(c + 64) * KTOT + rbase;
  const float sl = *s_lo_p, sh = *s_hi_p;
#pragma unroll
  for (int i = 0; i < 2; ++i) {
    f32x4 lo = *reinterpret_cast<const f32x4*>(pl + 4 * i);
    f32x4 hv = *reinterpret_cast<const f32x4*>(ph + 4 * i);
#pragma unroll
    for (int k = 1; k < KSPLIT; ++k) {
      lo += *reinterpret_cast<const f32x4*>(pl + (size_t)k * 128 * KTOT + 4 * i);
      hv += *reinterpret_cast<const f32x4*>(ph + (size_t)k * 128 * KTOT + 4 * i);
    }
    *reinterpret_cast<uint2*>((unsigned short*)bt_lo + (size_t)c * KTOT + rbase + 4 * i) =
        pack4(lo);
#pragma unroll
    for (int j = 0; j < 4; ++j) {
      int row = rbase + 4 * i + j;
      out[(size_t)row * 128 + 64 + c] = sl * lo[j] + sh * hv[j];
    }
  }
}

extern "C" void kernel_launch(void* const* d_in, const int* in_sizes, int n_in,
                              void* d_out, int out_size, void* d_ws, size_t ws_size,
                              hipStream_t stream) {
  const float* A_p = (const float*)d_in[0];
  const float* A_n = (const float*)d_in[1];
  const float* x_p = (const float*)d_in[2];
  const float* x_n = (const float*)d_in[3];
  const float* w_p = (const float*)d_in[4];  // [3]
  const float* w_n = (const float*)d_in[5];  // [3]
  float* out = (float*)d_out;                // [8192][128]

  // ws layout:
  //   BTbig [192][8192] bf16 (3 MiB) | B3T [128][8192] bf16 (2 MiB)
  //   part  [KSPLIT][128][8192] f32 (16 MiB)
  //   ablk  blocked bf16 A_p tile images (128 MiB) — if ws_size allows
  __hip_bfloat16* BTbig = (__hip_bfloat16*)d_ws;
  __hip_bfloat16* B3T = BTbig + (size_t)192 * KTOT;
  float* part = (float*)(B3T + (size_t)128 * KTOT);
  unsigned char* ablk = (unsigned char*)(part + (size_t)KSPLIT * 128 * KTOT);
  const size_t base_need = (size_t)192 * KTOT * 2 + (size_t)128 * KTOT * 2 +
                           (size_t)KSPLIT * 128 * KTOT * 4;
  const size_t blk_need = (size_t)KTOT * KTOT * 2;   // 128 MiB
  const bool use_blk = ws_size >= base_need + blk_need;

  xpose_f32_bf16<<<128, 256, 0, stream>>>(x_p, BTbig);
  xpose_f32_bf16<<<128, 256, 0, stream>>>(x_n, BTbig + (size_t)64 * KTOT);

  // G1: [P1|Y1] = A_p @ [x_p|x_n]  (+ emit blocked bf16 A_p if ws allows)
  if (use_blk)
    gemm_part<1><<<512, 512, 0, stream>>>(A_p, BTbig, part, ablk);
  else
    gemm_part<0><<<512, 512, 0, stream>>>(A_p, BTbig, part, nullptr);
  reduce_sep<<<256, 256, 0, stream>>>(part, out, w_p + 1, nullptr, x_p, w_p + 0,
                                      B3T, BTbig + (size_t)128 * KTOT, 0, -1, 0);

  // G2': [T1|T3] = A_n @ [x_n|Y1]
  gemm_part<0><<<512, 512, 0, stream>>>(A_n, BTbig + (size_t)64 * KTOT, part,
                                        nullptr);
  reduce_comb<<<256, 256, 0, stream>>>(part, out, w_n + 0, w_n + 2,
                                       B3T + (size_t)64 * KTOT);

  // G3: [P2|T2] = A_p @ [P1|T1] — from blocked bf16 A_p if available
  if (use_blk)
    gemm_blocked<<<512, 512, 0, stream>>>(ablk, B3T, part);
  else
    gemm_part<0><<<512, 512, 0, stream>>>(A_p, B3T, part, nullptr);
  reduce_sep<<<256, 256, 0, stream>>>(part, out, w_p + 2, w_n + 1, nullptr, nullptr,
                                      nullptr, nullptr, 0, 64, 1);
}

// Round 18
// 202.807 us; speedup vs baseline: 1.6533x; 1.0718x over previous
//
#include <hip/hip_runtime.h>
#include <hip/hip_bf16.h>
#include <stdint.h>

#define KTOT 8192
#define BM 128
#define BK 128
#define KSPLIT 4
#define KCHUNK (KTOT / KSPLIT)   // 2048
#define NIT (KCHUNK / BK)        // 16
#define TILE_BYTES (BM * BK * 2) // 32 KiB blocked-A tile image

typedef __attribute__((ext_vector_type(8))) __bf16 bf16x8;
typedef __attribute__((ext_vector_type(4))) float f32x4;

__device__ __forceinline__ unsigned short f2bf(float f) {
  union { float f; unsigned int u; } a;
  a.f = f;
  unsigned int r = (a.u + 0x7fffu + ((a.u >> 16) & 1u)) >> 16;
  return (unsigned short)r;
}

__device__ __forceinline__ uint2 pack4(f32x4 v) {
  union { unsigned short h[4]; uint2 u; } pk;
  pk.h[0] = f2bf(v[0]); pk.h[1] = f2bf(v[1]);
  pk.h[2] = f2bf(v[2]); pk.h[3] = f2bf(v[3]);
  return pk.u;
}

// Barrier that drains LDS only — global prefetches stay in flight (T4).
__device__ __forceinline__ void block_bar() {
  asm volatile("s_waitcnt lgkmcnt(0)" ::: "memory");
  __builtin_amdgcn_s_barrier();
  __builtin_amdgcn_sched_barrier(0);
}

// x [8192][64] f32  ->  xt [64][8192] bf16 (transposed)
__global__ __launch_bounds__(256) void xpose_f32_bf16(const float* __restrict__ x,
                                                      __hip_bfloat16* __restrict__ xt) {
  __shared__ unsigned short tile[64][72];
  const int r0 = blockIdx.x * 64;
  const int t = threadIdx.x;
  const int a = t >> 4;
  const int c4 = (t & 15) * 4;
#pragma unroll
  for (int rep = 0; rep < 4; ++rep) {
    int r = a + rep * 16;
    f32x4 v = __builtin_nontemporal_load(
        reinterpret_cast<const f32x4*>(x + (size_t)(r0 + r) * 64 + c4));
    tile[c4 + 0][r] = f2bf(v[0]);
    tile[c4 + 1][r] = f2bf(v[1]);
    tile[c4 + 2][r] = f2bf(v[2]);
    tile[c4 + 3][r] = f2bf(v[3]);
  }
  __syncthreads();
#pragma unroll
  for (int rep = 0; rep < 4; ++rep) {
    int j = a + rep * 16;
    uint2 v = *reinterpret_cast<const uint2*>(&tile[j][c4]);
    *reinterpret_cast<uint2*>((unsigned short*)xt + (size_t)j * KTOT + r0 + c4) = v;
  }
}

// part[kc][col][row] (f32, [KSPLIT][128][8192]) partials of C = A @ B,
// BT[128][8192] bf16. BM=128 (halved B traffic vs BM=64): grid 256 = 1
// block/CU. A reg->bf16->LDS (XOR swizzle) dbuf, depth-2 reg prefetch;
// B direct global->reg; lgkm-only barriers; K-phase rotation; XCD-affine
// kc. Partial stores REGULAR (L3-retained). WBLK=1 emits blocked bf16 A.
template <int WBLK>
__global__ __launch_bounds__(512, 2) void gemm_part(
    const float* __restrict__ A, const __hip_bfloat16* __restrict__ BTv,
    float* __restrict__ part, unsigned char* __restrict__ ablk) {
  constexpr int SZ_A = BM * BK * 2;   // 32 KiB
  __shared__ __align__(16) unsigned char smem[2 * SZ_A];   // 64 KiB
  const unsigned short* BT = (const unsigned short*)BTv;

  const int bid = blockIdx.x;
  const int kc = (bid & 7) >> 1;                 // XCD-affine K-chunk
  const int mblk = ((bid >> 3) << 1) | (bid & 1); // 0..63
  const int r0 = mblk * BM;
  const int kbase = kc * KCHUNK;
  const int it0 = mblk & (NIT - 1);              // K-phase rotation

  const int t = threadIdx.x;
  const int l = t & 63;
  const int w = t >> 6;

  // ---- A staging: 128x128 f32 tile, 8 f32x4 per thread ----
  const float* aptr[8];
  int loff[8];
#pragma unroll
  for (int r = 0; r < 8; ++r) {
    int idx = t + r * 512;
    int m = idx >> 5, c4 = idx & 31;             // row 0..127, f32x4-col 0..31
    aptr[r] = A + (size_t)(r0 + m) * KTOT + kbase + c4 * 4;
    loff[r] = m * 256 + ((c4 * 8) ^ ((m & 7) << 4));
  }
  unsigned char* tb0 =
      WBLK ? ablk + (size_t)(mblk * KSPLIT + kc) * NIT * TILE_BYTES : nullptr;

  const int lr = l & 15;
  const int g = l >> 4;
  const int col = w * 16 + lr;
  const unsigned short* bptr = BT + (size_t)col * KTOT + kbase + g * 8;
  const int asw = (lr & 7) << 4;

  f32x4 acc[8];
  const f32x4 fzero = {0.f, 0.f, 0.f, 0.f};
#pragma unroll
  for (int mt = 0; mt < 8; ++mt) acc[mt] = fzero;

  f32x4 av0[8], av1[8];
  bf16x8 Bf0[4], Bf1[4];
  unsigned char* lds0 = smem;
  unsigned char* lds1 = smem + SZ_A;

  auto kof = [&](int s) { return ((s + it0) & (NIT - 1)) * BK; };

#define LOAD_A(AV, K0)                                                        \
  _Pragma("unroll") for (int r = 0; r < 8; ++r)                               \
      AV[r] = __builtin_nontemporal_load(                                     \
          reinterpret_cast<const f32x4*>(aptr[r] + (K0)));
#define LOAD_B(BF, K0)                                                        \
  _Pragma("unroll") for (int ks = 0; ks < 4; ++ks)                            \
      BF[ks] = *reinterpret_cast<const bf16x8*>(bptr + (K0) + ks * 32);
#define WRITE_A(LDS, AV, RS)                                                  \
  _Pragma("unroll") for (int r = 0; r < 8; ++r) {                             \
    uint2 pk_ = pack4(AV[r]);                                                 \
    *reinterpret_cast<uint2*>((LDS) + loff[r]) = pk_;                         \
    if constexpr (WBLK)                                                       \
      *reinterpret_cast<uint2*>(tb0 + (size_t)(RS) * TILE_BYTES + loff[r]) =  \
          pk_;                                                                \
  }
#define COMPUTE(LDS, BF)                                                      \
  _Pragma("unroll") for (int ks = 0; ks < 4; ++ks) {                          \
    _Pragma("unroll") for (int mt = 0; mt < 8; ++mt) {                        \
      bf16x8 af_ = *reinterpret_cast<const bf16x8*>(                          \
          (LDS) + (mt * 16 + lr) * 256 + ((ks * 64 + g * 16) ^ asw));         \
      acc[mt] = __builtin_amdgcn_mfma_f32_16x16x32_bf16(af_, BF[ks], acc[mt], \
                                                        0, 0, 0);             \
    }                                                                         \
  }

  LOAD_A(av0, kof(0)); LOAD_B(Bf0, kof(0));
  LOAD_A(av1, kof(1)); LOAD_B(Bf1, kof(1));
  WRITE_A(lds0, av0, it0);
  block_bar();

#pragma unroll 1
  for (int s = 0; s < NIT; s += 2) {
    if (s + 1 < NIT) { WRITE_A(lds1, av1, (s + 1 + it0) & (NIT - 1)); }
    if (s + 2 < NIT) { LOAD_A(av0, kof(s + 2)); }
    COMPUTE(lds0, Bf0);
    if (s + 2 < NIT) { LOAD_B(Bf0, kof(s + 2)); }
    if (s + 1 < NIT) block_bar();
    if (s + 1 < NIT) {
      if (s + 2 < NIT) { WRITE_A(lds0, av0, (s + 2 + it0) & (NIT - 1)); }
      if (s + 3 < NIT) { LOAD_A(av1, kof(s + 3)); }
      COMPUTE(lds1, Bf1);
      if (s + 3 < NIT) { LOAD_B(Bf1, kof(s + 3)); }
      if (s + 2 < NIT) block_bar();
    }
  }

  // REGULAR partial store — L3-retained for the reduce pass.
  float* pp = part + (size_t)(kc * 128 + col) * KTOT + r0 + g * 4;
#pragma unroll
  for (int mt = 0; mt < 8; ++mt)
    *reinterpret_cast<f32x4*>(pp + mt * 16) = acc[mt];
#undef LOAD_A
#undef WRITE_A
}

// G3 variant: A from blocked bf16 tile images (dense 512 KB slab per block).
__global__ __launch_bounds__(512, 2) void gemm_blocked(
    const unsigned char* __restrict__ ablk, const __hip_bfloat16* __restrict__ BTv,
    float* __restrict__ part) {
  constexpr int SZ_A = BM * BK * 2;
  __shared__ __align__(16) unsigned char smem[2 * SZ_A];
  const unsigned short* BT = (const unsigned short*)BTv;

  const int bid = blockIdx.x;
  const int kc = (bid & 7) >> 1;
  const int mblk = ((bid >> 3) << 1) | (bid & 1);
  const int r0 = mblk * BM;
  const int kbase = kc * KCHUNK;
  const int it0 = mblk & (NIT - 1);

  const int t = threadIdx.x;
  const int l = t & 63;
  const int w = t >> 6;

  int loff[8];
#pragma unroll
  for (int r = 0; r < 8; ++r) {
    int idx = t + r * 512;
    int m = idx >> 5, c4 = idx & 31;
    loff[r] = m * 256 + ((c4 * 8) ^ ((m & 7) << 4));
  }
  const unsigned char* tb0 =
      ablk + (size_t)(mblk * KSPLIT + kc) * NIT * TILE_BYTES;

  const int lr = l & 15;
  const int g = l >> 4;
  const int col = w * 16 + lr;
  const unsigned short* bptr = BT + (size_t)col * KTOT + kbase + g * 8;
  const int asw = (lr & 7) << 4;

  f32x4 acc[8];
  const f32x4 fzero = {0.f, 0.f, 0.f, 0.f};
#pragma unroll
  for (int mt = 0; mt < 8; ++mt) acc[mt] = fzero;

  uint2 bv0[8], bv1[8];
  bf16x8 Bf0[4], Bf1[4];
  unsigned char* lds0 = smem;
  unsigned char* lds1 = smem + SZ_A;

  auto kof = [&](int s) { return ((s + it0) & (NIT - 1)) * BK; };
  auto rs = [&](int s) { return (s + it0) & (NIT - 1); };

#define LOAD_A(BV, RS)                                                        \
  _Pragma("unroll") for (int r = 0; r < 8; ++r)                               \
      BV[r] = *reinterpret_cast<const uint2*>(                                \
          tb0 + (size_t)(RS) * TILE_BYTES + loff[r]);
#define LOAD_B(BF, K0)                                                        \
  _Pragma("unroll") for (int ks = 0; ks < 4; ++ks)                            \
      BF[ks] = *reinterpret_cast<const bf16x8*>(bptr + (K0) + ks * 32);
#define WRITE_A(LDS, BV)                                                      \
  _Pragma("unroll") for (int r = 0; r < 8; ++r)                               \
      *reinterpret_cast<uint2*>((LDS) + loff[r]) = BV[r];
#define COMPUTE(LDS, BF)                                                      \
  _Pragma("unroll") for (int ks = 0; ks < 4; ++ks) {                          \
    _Pragma("unroll") for (int mt = 0; mt < 8; ++mt) {                        \
      bf16x8 af_ = *reinterpret_cast<const bf16x8*>(                          \
          (LDS) + (mt * 16 + lr) * 256 + ((ks * 64 + g * 16) ^ asw));         \
      acc[mt] = __builtin_amdgcn_mfma_f32_16x16x32_bf16(af_, BF[ks], acc[mt], \
                                                        0, 0, 0);             \
    }                                                                         \
  }

  LOAD_A(bv0, rs(0)); LOAD_B(Bf0, kof(0));
  LOAD_A(bv1, rs(1)); LOAD_B(Bf1, kof(1));
  WRITE_A(lds0, bv0);
  block_bar();

#pragma unroll 1
  for (int s = 0; s < NIT; s += 2) {
    if (s + 1 < NIT) { WRITE_A(lds1, bv1); }
    if (s + 2 < NIT) { LOAD_A(bv0, rs(s + 2)); }
    COMPUTE(lds0, Bf0);
    if (s + 2 < NIT) { LOAD_B(Bf0, kof(s + 2)); }
    if (s + 1 < NIT) block_bar();
    if (s + 1 < NIT) {
      if (s + 2 < NIT) { WRITE_A(lds0, bv0); }
      if (s + 3 < NIT) { LOAD_A(bv1, rs(s + 3)); }
      COMPUTE(lds1, Bf1);
      if (s + 3 < NIT) { LOAD_B(Bf1, kof(s + 3)); }
      if (s + 2 < NIT) block_bar();
    }
  }

  float* pp = part + (size_t)(kc * 128 + col) * KTOT + r0 + g * 4;
#pragma unroll
  for (int mt = 0; mt < 8; ++mt)
    *reinterpret_cast<f32x4*>(pp + mt * 16) = acc[mt];
#undef LOAD_A
#undef LOAD_B
#undef WRITE_A
#undef COMPUTE
}

// Combine KSPLIT partials + epilogue, separate halves (lo: cols 0-63, hi: 64-127).
__global__ __launch_bounds__(256) void reduce_sep(
    const float* __restrict__ part, float* __restrict__ out,
    const float* s_lo_p, const float* s_hi_p,
    const float* __restrict__ add_ptr, const float* add_s_p,
    __hip_bfloat16* bt_lo, __hip_bfloat16* bt_hi,
    int base_lo, int base_hi, int accum) {
  const int t = threadIdx.x;
  const int col = t & 127;
  const int rbase = blockIdx.x * 32 + (t >> 7) * 16;
  const float* p0 = part + (size_t)col * KTOT + rbase;
  const bool hi = col >= 64;
  const int col64 = hi ? col - 64 : col;
  __hip_bfloat16* bt = hi ? bt_hi : bt_lo;
  const int obase = hi ? base_hi : base_lo;
  const float s = hi ? (s_hi_p ? *s_hi_p : 0.f) : (s_lo_p ? *s_lo_p : 0.f);
  const float was = add_s_p ? *add_s_p : 0.f;
#pragma unroll
  for (int i = 0; i < 4; ++i) {
    f32x4 c = *reinterpret_cast<const f32x4*>(p0 + 4 * i);
#pragma unroll
    for (int k = 1; k < KSPLIT; ++k)
      c += *reinterpret_cast<const f32x4*>(p0 + (size_t)k * 128 * KTOT + 4 * i);
    if (bt)
      *reinterpret_cast<uint2*>((unsigned short*)bt + (size_t)col64 * KTOT + rbase + 4 * i) =
          pack4(c);
    if (obase >= 0) {
#pragma unroll
      for (int j = 0; j < 4; ++j) {
        int row = rbase + 4 * i + j;
        float v = s * c[j];
        if (add_ptr && !hi) v = fmaf(was, add_ptr[(size_t)row * 64 + col64], v);
        if (accum) v += out[(size_t)row * 128 + obase + col64];
        out[(size_t)row * 128 + obase + col64] = v;
      }
    }
  }
}

// Combine partials + cross-half epilogue: out[:,64+c] = sl*lo[c] + sh*hi[c];
// bt_lo = raw lo (bf16 transposed).
__global__ __launch_bounds__(256) void reduce_comb(
    const float* __restrict__ part, float* __restrict__ out,
    const float* s_lo_p, const float* s_hi_p, __hip_bfloat16* bt_lo) {
  const int t = threadIdx.x;
  const int c = t & 63;
  const int rbase = blockIdx.x * 32 + (t >> 6) * 8;
  const float* pl = part + (size_t)c * KTOT + rbase;
  const float* ph = part + (size_t)(c + 64) * KTOT + rbase;
  const float sl = *s_lo_p, sh = *s_hi_p;
#pragma unroll
  for (int i = 0; i < 2; ++i) {
    f32x4 lo = *reinterpret_cast<const f32x4*>(pl + 4 * i);
    f32x4 hv = *reinterpret_cast<const f32x4*>(ph + 4 * i);
#pragma unroll
    for (int k = 1; k < KSPLIT; ++k) {
      lo += *reinterpret_cast<const f32x4*>(pl + (size_t)k * 128 * KTOT + 4 * i);
      hv += *reinterpret_cast<const f32x4*>(ph + (size_t)k * 128 * KTOT + 4 * i);
    }
    *reinterpret_cast<uint2*>((unsigned short*)bt_lo + (size_t)c * KTOT + rbase + 4 * i) =
        pack4(lo);
#pragma unroll
    for (int j = 0; j < 4; ++j) {
      int row = rbase + 4 * i + j;
      out[(size_t)row * 128 + 64 + c] = sl * lo[j] + sh * hv[j];
    }
  }
}

extern "C" void kernel_launch(void* const* d_in, const int* in_sizes, int n_in,
                              void* d_out, int out_size, void* d_ws, size_t ws_size,
                              hipStream_t stream) {
  const float* A_p = (const float*)d_in[0];
  const float* A_n = (const float*)d_in[1];
  const float* x_p = (const float*)d_in[2];
  const float* x_n = (const float*)d_in[3];
  const float* w_p = (const float*)d_in[4];  // [3]
  const float* w_n = (const float*)d_in[5];  // [3]
  float* out = (float*)d_out;                // [8192][128]

  // ws layout:
  //   BTbig [192][8192] bf16 (3 MiB) | B3T [128][8192] bf16 (2 MiB)
  //   part  [KSPLIT][128][8192] f32 (16 MiB)
  //   ablk  blocked bf16 A_p tile images (128 MiB) — if ws_size allows
  __hip_bfloat16* BTbig = (__hip_bfloat16*)d_ws;
  __hip_bfloat16* B3T = BTbig + (size_t)192 * KTOT;
  float* part = (float*)(B3T + (size_t)128 * KTOT);
  unsigned char* ablk = (unsigned char*)(part + (size_t)KSPLIT * 128 * KTOT);
  const size_t base_need = (size_t)192 * KTOT * 2 + (size_t)128 * KTOT * 2 +
                           (size_t)KSPLIT * 128 * KTOT * 4;
  const size_t blk_need = (size_t)KTOT * KTOT * 2;   // 128 MiB
  const bool use_blk = ws_size >= base_need + blk_need;

  xpose_f32_bf16<<<128, 256, 0, stream>>>(x_p, BTbig);
  xpose_f32_bf16<<<128, 256, 0, stream>>>(x_n, BTbig + (size_t)64 * KTOT);

  // G1: [P1|Y1] = A_p @ [x_p|x_n]  (+ emit blocked bf16 A_p if ws allows)
  if (use_blk)
    gemm_part<1><<<256, 512, 0, stream>>>(A_p, BTbig, part, ablk);
  else
    gemm_part<0><<<256, 512, 0, stream>>>(A_p, BTbig, part, nullptr);
  reduce_sep<<<256, 256, 0, stream>>>(part, out, w_p + 1, nullptr, x_p, w_p + 0,
                                      B3T, BTbig + (size_t)128 * KTOT, 0, -1, 0);

  // G2': [T1|T3] = A_n @ [x_n|Y1]
  gemm_part<0><<<256, 512, 0, stream>>>(A_n, BTbig + (size_t)64 * KTOT, part,
                                        nullptr);
  reduce_comb<<<256, 256, 0, stream>>>(part, out, w_n + 0, w_n + 2,
                                       B3T + (size_t)64 * KTOT);

  // G3: [P2|T2] = A_p @ [P1|T1] — from blocked bf16 A_p if available
  if (use_blk)
    gemm_blocked<<<256, 512, 0, stream>>>(ablk, B3T, part);
  else
    gemm_part<0><<<256, 512, 0, stream>>>(A_p, B3T, part, nullptr);
  reduce_sep<<<256, 256, 0, stream>>>(part, out, w_p + 2, w_n + 1, nullptr, nullptr,
                                      nullptr, nullptr, 0, 64, 1);
}